// Round 8
// baseline (442.679 us; speedup 1.0000x reference)
//
#include <hip/hip_runtime.h>
#include <hip/hip_bf16.h>

#define NN 50000
#define EE 800000

typedef short short8 __attribute__((ext_vector_type(8)));
typedef float f32x4 __attribute__((ext_vector_type(4)));

union Frag16B { short8 s; int4 i; };
union H4 { _Float16 h[4]; uint2 u; };

static __device__ __forceinline__ unsigned short f2bf(float f) {
    union { float f; unsigned u; } v; v.f = f;
    unsigned r = v.u + 0x7FFF + ((v.u >> 16) & 1);   // RNE
    return (unsigned short)(r >> 16);
}
static __device__ __forceinline__ float bf_lo(unsigned int u) {
    return __uint_as_float(u << 16);
}
static __device__ __forceinline__ float bf_hi(unsigned int u) {
    return __uint_as_float(u & 0xFFFF0000u);
}
static __device__ __forceinline__ unsigned int pack2(float a, float b) {
    return (unsigned int)f2bf(a) | ((unsigned int)f2bf(b) << 16);
}

// ---------------- prep: fragment-major bf16 weight packing + pos->float4 ----
__global__ __launch_bounds__(256) void k_prep(
    const float* __restrict__ w1,  const float* __restrict__ att,
    const float* __restrict__ w2,
    const float* __restrict__ wft, const float* __restrict__ wcv,
    const float* __restrict__ pos,
    unsigned short* __restrict__ w1p, unsigned short* __restrict__ w2p,
    unsigned short* __restrict__ wftp, unsigned short* __restrict__ wcvp,
    float4* __restrict__ pos4)
{
    int gth = blockIdx.x * 256 + threadIdx.x;
    int lane = gth & 63, l15 = lane & 15, gg = lane >> 4;
    if (gth < 16384) {                       // w1p: kk<16, t<16, fold att[col]
        int t = (gth >> 6) & 15, kk = gth >> 10;
        int row = t * 16 + l15, c0 = kk * 32 + gg * 8;
        unsigned int pk[4];
        #pragma unroll
        for (int j = 0; j < 4; ++j) {
            int c = c0 + 2 * j;
            pk[j] = pack2(w1[row * 512 + c] * att[c],
                          w1[row * 512 + c + 1] * att[c + 1]);
        }
        *reinterpret_cast<uint4*>(w1p + (size_t)gth * 8) = make_uint4(pk[0], pk[1], pk[2], pk[3]);
    }
    if (gth < 4096) {                        // w2p: kk<8, t<8
        int t = (gth >> 6) & 7, kk = gth >> 9;
        int row = t * 16 + l15, c0 = kk * 32 + gg * 8;
        unsigned int pk[4];
        #pragma unroll
        for (int j = 0; j < 4; ++j) {
            int c = c0 + 2 * j;
            pk[j] = pack2(w2[row * 256 + c], w2[row * 256 + c + 1]);
        }
        *reinterpret_cast<uint4*>(w2p + (size_t)gth * 8) = make_uint4(pk[0], pk[1], pk[2], pk[3]);
    }
    if (gth < 2048) {                        // wftp / wcvp: kk<4, t<8
        int t = (gth >> 6) & 7, kk = gth >> 9;
        int row = t * 16 + l15, c0 = kk * 32 + gg * 8;
        unsigned int pa[4], pb[4];
        #pragma unroll
        for (int j = 0; j < 4; ++j) {
            int c = c0 + 2 * j;
            pa[j] = pack2(wft[row * 128 + c], wft[row * 128 + c + 1]);
            pb[j] = pack2(wcv[row * 128 + c], wcv[row * 128 + c + 1]);
        }
        *reinterpret_cast<uint4*>(wftp + (size_t)gth * 8) = make_uint4(pa[0], pa[1], pa[2], pa[3]);
        *reinterpret_cast<uint4*>(wcvp + (size_t)gth * 8) = make_uint4(pb[0], pb[1], pb[2], pb[3]);
    }
    if (gth < NN) {                          // pos -> padded float4
        pos4[gth] = make_float4(pos[gth * 3 + 0], pos[gth * 3 + 1], pos[gth * 3 + 2], 0.f);
    }
}

// ---------------- fused node GEMMs (MFMA): msg = (relu(x WftT+bft)) WcvT + bcv
__global__ __launch_bounds__(256) void k_ft_conv(
    const float* __restrict__ x,
    const unsigned short* __restrict__ wftp, const float* __restrict__ bft,
    const unsigned short* __restrict__ wcvp, const float* __restrict__ bcv,
    unsigned int* __restrict__ msg)          // bf16 [NN][128] as uint[NN][64]
{
    __shared__ unsigned int s_x[64 * 68];    // bf16 tile (reused for out)
    __shared__ unsigned short s_h[64 * 136];
    const int tid = threadIdx.x;
    const int w = tid >> 6, lane = tid & 63, l15 = lane & 15, g = lane >> 4;
    const int n0 = blockIdx.x * 64;

    #pragma unroll
    for (int i = 0; i < 8; ++i) {
        int lin = tid + i * 256;
        int row = lin >> 5, c4 = lin & 31;
        int ar = (n0 + row < NN) ? n0 + row : NN - 1;
        float4 v = *reinterpret_cast<const float4*>(x + (size_t)ar * 128 + c4 * 4);
        s_x[row * 68 + c4 * 2]     = pack2(v.x, v.y);
        s_x[row * 68 + c4 * 2 + 1] = pack2(v.z, v.w);
    }
    __syncthreads();

    float bftv[8], bcvv[8];
    #pragma unroll
    for (int t = 0; t < 8; ++t) { bftv[t] = bft[t * 16 + l15]; bcvv[t] = bcv[t * 16 + l15]; }

    const int4* Bf = reinterpret_cast<const int4*>(wftp);
    f32x4 acc[8];
    #pragma unroll
    for (int t = 0; t < 8; ++t) acc[t] = (f32x4){0.f, 0.f, 0.f, 0.f};
    #pragma unroll
    for (int kk = 0; kk < 4; ++kk) {
        Frag16B a;
        a.i = *reinterpret_cast<const int4*>(&s_x[(w * 16 + l15) * 68 + kk * 16 + g * 4]);
        #pragma unroll
        for (int t = 0; t < 8; ++t) {
            Frag16B b; b.i = Bf[(kk * 8 + t) * 64 + lane];
            acc[t] = __builtin_amdgcn_mfma_f32_16x16x32_bf16(a.s, b.s, acc[t], 0, 0, 0);
        }
    }
    #pragma unroll
    for (int t = 0; t < 8; ++t)
        #pragma unroll
        for (int r = 0; r < 4; ++r)
            s_h[(w * 16 + g * 4 + r) * 136 + t * 16 + l15] =
                f2bf(fmaxf(acc[t][r] + bftv[t], 0.f));
    __syncthreads();

    const int4* Bc = reinterpret_cast<const int4*>(wcvp);
    #pragma unroll
    for (int t = 0; t < 8; ++t) acc[t] = (f32x4){0.f, 0.f, 0.f, 0.f};
    #pragma unroll
    for (int kk = 0; kk < 4; ++kk) {
        Frag16B a;
        a.i = *reinterpret_cast<const int4*>(&s_h[(w * 16 + l15) * 136 + kk * 32 + g * 8]);
        #pragma unroll
        for (int t = 0; t < 8; ++t) {
            Frag16B b; b.i = Bc[(kk * 8 + t) * 64 + lane];
            acc[t] = __builtin_amdgcn_mfma_f32_16x16x32_bf16(a.s, b.s, acc[t], 0, 0, 0);
        }
    }
    unsigned short* s_o = reinterpret_cast<unsigned short*>(s_x);
    #pragma unroll
    for (int t = 0; t < 8; ++t)
        #pragma unroll
        for (int r = 0; r < 4; ++r)
            s_o[(w * 16 + g * 4 + r) * 136 + t * 16 + l15] = f2bf(acc[t][r] + bcvv[t]);
    __syncthreads();
    #pragma unroll
    for (int i = 0; i < 8; ++i) {
        int lin = tid + i * 256;
        int row = lin >> 5, cu2 = lin & 31;
        if (n0 + row < NN) {
            uint2 v;
            v.x = s_x[row * 68 + cu2 * 2];
            v.y = s_x[row * 68 + cu2 * 2 + 1];
            *reinterpret_cast<uint2*>(msg + (size_t)(n0 + row) * 64 + cu2 * 2) = v;
        }
    }
}

// ---------------- edge pass 1: {dist,dsum,s,d} record + degree + block max --
__global__ __launch_bounds__(256) void k_edge_pass1(
    const int* __restrict__ ei, const float4* __restrict__ pos4,
    float* __restrict__ blockmax, int* __restrict__ counts,
    float4* __restrict__ dde)
{
    __shared__ float smax[4];
    int e = blockIdx.x * 256 + threadIdx.x;       // grid covers EE exactly
    int s = ei[e], d = ei[EE + e];
    float4 ps = pos4[s], pd = pos4[d];
    float dx = ps.x - pd.x, dy = ps.y - pd.y, dz = ps.z - pd.z;
    float dist = sqrtf(dx * dx + dy * dy + dz * dz);
    float rinv = 1.f / (dist + 1e-8f);
    dde[e] = make_float4(dist, (dx + dy + dz) * rinv,
                         __int_as_float(s), __int_as_float(d));
    atomicAdd(&counts[d], 1);

    float m = dist;
    #pragma unroll
    for (int o = 32; o >= 1; o >>= 1)
        m = fmaxf(m, __shfl_xor(m, o));
    if ((threadIdx.x & 63) == 0) smax[threadIdx.x >> 6] = m;
    __syncthreads();
    if (threadIdx.x == 0)
        blockmax[blockIdx.x] = fmaxf(fmaxf(smax[0], smax[1]), fmaxf(smax[2], smax[3]));
}

// ---------------- 3-kernel exclusive scan over counts -----------------------
__global__ __launch_bounds__(256) void k_scan1(const int* __restrict__ counts,
    int* __restrict__ loc, int* __restrict__ bsum)
{
    __shared__ int sd[256];
    int i = blockIdx.x * 256 + threadIdx.x;
    int v = (i < NN) ? counts[i] : 0;
    sd[threadIdx.x] = v;
    __syncthreads();
    for (int ofs = 1; ofs < 256; ofs <<= 1) {
        int t = (threadIdx.x >= ofs) ? sd[threadIdx.x - ofs] : 0;
        __syncthreads();
        sd[threadIdx.x] += t;
        __syncthreads();
    }
    int incl = sd[threadIdx.x];
    if (i < NN) loc[i] = incl - v;
    if (threadIdx.x == 255) bsum[blockIdx.x] = incl;
}

// block 0: exclusive scan of bsum; block 1: dmax reduce over blockmax
__global__ __launch_bounds__(256) void k_scan2dmax(const int* __restrict__ bsum,
    int* __restrict__ bofs, int nb,
    const float* __restrict__ blockmax, float* __restrict__ dmax, int nmb)
{
    if (blockIdx.x == 0) {
        __shared__ int sd[256];
        int v = (threadIdx.x < nb) ? bsum[threadIdx.x] : 0;
        sd[threadIdx.x] = v;
        __syncthreads();
        for (int ofs = 1; ofs < 256; ofs <<= 1) {
            int t = (threadIdx.x >= ofs) ? sd[threadIdx.x - ofs] : 0;
            __syncthreads();
            sd[threadIdx.x] += t;
            __syncthreads();
        }
        bofs[threadIdx.x] = sd[threadIdx.x] - v;
    } else {
        __shared__ float smax[4];
        float m = 0.f;
        for (int i = threadIdx.x; i < nmb; i += 256) m = fmaxf(m, blockmax[i]);
        #pragma unroll
        for (int o = 32; o >= 1; o >>= 1)
            m = fmaxf(m, __shfl_xor(m, o));
        if ((threadIdx.x & 63) == 0) smax[threadIdx.x >> 6] = m;
        __syncthreads();
        if (threadIdx.x == 0)
            dmax[0] = fmaxf(fmaxf(smax[0], smax[1]), fmaxf(smax[2], smax[3]));
    }
}

__global__ __launch_bounds__(256) void k_scan3(const int* __restrict__ loc,
    const int* __restrict__ bofs, int* __restrict__ offs)
{
    int i = blockIdx.x * 256 + threadIdx.x;
    if (i < NN) offs[i] = loc[i] + bofs[blockIdx.x];
    if (i == 0) offs[NN] = EE;
}

// ---------------- edge pass 2: ab factors + packed CSR record ---------------
__global__ __launch_bounds__(256) void k_fill(
    const float4* __restrict__ dde,
    const float* __restrict__ dmaxp,
    const float* __restrict__ vfp, const float* __restrict__ vpar,
    const int* __restrict__ offs, int* __restrict__ cursor,
    uint4* __restrict__ csre)
{
    int e = blockIdx.x * 256 + threadIdx.x;       // grid covers EE exactly
    float4 v4 = dde[e];
    int s = __float_as_int(v4.z), d = __float_as_int(v4.w);
    float r = v4.x / dmaxp[0];
    float dsum = v4.y;
    float vf = vfp[0];
    H4 p;
    #pragma unroll
    for (int k = 0; k < 4; ++k) {
        float v = vf * fminf(r, vpar[k]);
        p.h[k] = (_Float16)(sqrtf(1.f - v * v + 1e-8f) / (1.f + v * dsum));
    }
    int slot = offs[d] + atomicAdd(&cursor[d], 1);
    csre[slot] = make_uint4((unsigned)s, p.u.x, p.u.y, 0u);
}

// ---------------- aggregation: one wave per node, 8x unrolled gathers -------
__global__ __launch_bounds__(256) void k_agg(
    const int* __restrict__ offs, const uint4* __restrict__ csre,
    const unsigned int* __restrict__ msg,
    unsigned int* __restrict__ aggb)         // bf16 [NN][512] as uint[NN][256]
{
    int lane = threadIdx.x & 63;
    int n = blockIdx.x * 4 + (threadIdx.x >> 6);
    if (n >= NN) return;
    int st = offs[n], en = offs[n + 1];
    float a00 = 0, a10 = 0, a20 = 0, a30 = 0, a01 = 0, a11 = 0, a21 = 0, a31 = 0;

    int e = st;
    for (; e + 8 <= en; e += 8) {
        uint4 rr[8];
        unsigned int uu[8];
        #pragma unroll
        for (int j = 0; j < 8; ++j) rr[j] = csre[e + j];
        #pragma unroll
        for (int j = 0; j < 8; ++j) uu[j] = msg[(size_t)rr[j].x * 64 + lane];
        #pragma unroll
        for (int j = 0; j < 8; ++j) {
            H4 p; p.u = make_uint2(rr[j].y, rr[j].z);
            float m0 = bf_lo(uu[j]), m1 = bf_hi(uu[j]);
            a00 = fmaf((float)p.h[0], m0, a00); a01 = fmaf((float)p.h[0], m1, a01);
            a10 = fmaf((float)p.h[1], m0, a10); a11 = fmaf((float)p.h[1], m1, a11);
            a20 = fmaf((float)p.h[2], m0, a20); a21 = fmaf((float)p.h[2], m1, a21);
            a30 = fmaf((float)p.h[3], m0, a30); a31 = fmaf((float)p.h[3], m1, a31);
        }
    }
    for (; e < en; ++e) {
        uint4 rr = csre[e];
        unsigned int u = msg[(size_t)rr.x * 64 + lane];
        H4 p; p.u = make_uint2(rr.y, rr.z);
        float m0 = bf_lo(u), m1 = bf_hi(u);
        a00 = fmaf((float)p.h[0], m0, a00); a01 = fmaf((float)p.h[0], m1, a01);
        a10 = fmaf((float)p.h[1], m0, a10); a11 = fmaf((float)p.h[1], m1, a11);
        a20 = fmaf((float)p.h[2], m0, a20); a21 = fmaf((float)p.h[2], m1, a21);
        a30 = fmaf((float)p.h[3], m0, a30); a31 = fmaf((float)p.h[3], m1, a31);
    }

    unsigned int* o = aggb + (size_t)n * 256 + lane;   // col c = k*128 + h
    o[0]   = pack2(a00, a01);
    o[64]  = pack2(a10, a11);
    o[128] = pack2(a20, a21);
    o[192] = pack2(a30, a31);
}

// ---------------- BN stats: 32-row stripes into 32 partial buffers ----------
__global__ __launch_bounds__(256) void k_bnstats(const uint2* __restrict__ aggb2,
    float* __restrict__ bn_psum, float* __restrict__ bn_psq)
{
    int c2 = threadIdx.x & 127;              // uint2 col (owns cols 4*c2..4*c2+3)
    int rbase = blockIdx.x * 32 + (threadIdx.x >> 7);
    float s0 = 0, s1 = 0, s2 = 0, s3 = 0, q0 = 0, q1 = 0, q2 = 0, q3 = 0;
    #pragma unroll 8
    for (int i = 0; i < 16; ++i) {
        int r = rbase + 2 * i;
        if (r < NN) {
            uint2 u = aggb2[(size_t)r * 128 + c2];
            float v0 = bf_lo(u.x), v1 = bf_hi(u.x);
            float v2 = bf_lo(u.y), v3 = bf_hi(u.y);
            s0 += v0; s1 += v1; s2 += v2; s3 += v3;
            q0 = fmaf(v0, v0, q0); q1 = fmaf(v1, v1, q1);
            q2 = fmaf(v2, v2, q2); q3 = fmaf(v3, v3, q3);
        }
    }
    int part = (blockIdx.x & 31) * 512;
    int c0 = c2 * 4;
    atomicAdd(&bn_psum[part + c0], s0);     atomicAdd(&bn_psum[part + c0 + 1], s1);
    atomicAdd(&bn_psum[part + c0 + 2], s2); atomicAdd(&bn_psum[part + c0 + 3], s3);
    atomicAdd(&bn_psq[part + c0], q0);      atomicAdd(&bn_psq[part + c0 + 1], q1);
    atomicAdd(&bn_psq[part + c0 + 2], q2);  atomicAdd(&bn_psq[part + c0 + 3], q3);
}

__global__ __launch_bounds__(256) void k_bnfin(const float* __restrict__ bn_psum,
    const float* __restrict__ bn_psq, const float* __restrict__ bng,
    const float* __restrict__ bnbeta, float* __restrict__ bns, float* __restrict__ bnbv)
{
    int c = blockIdx.x * 256 + threadIdx.x;
    if (c >= 512) return;
    float s = 0.f, q = 0.f;
    #pragma unroll 8
    for (int p = 0; p < 32; ++p) {
        s += bn_psum[p * 512 + c];
        q += bn_psq[p * 512 + c];
    }
    float mean = s * (1.f / NN);
    float var = q * (1.f / NN) - mean * mean;
    float sc = bng[c] / sqrtf(var + 1e-5f);
    bns[c] = sc;
    bnbv[c] = bnbeta[c] - mean * sc;
}

// ---------------- final fused MFMA (K-chunked staging, 36.3 KB LDS) ---------
// No min-waves bound: VGPR must stay ~116 (R5-level) so acc1/acc2 live in regs;
// launch_bounds(256,4) forced 128-reg cap -> scratch spills (R7: +45 MB HBM).
__global__ __launch_bounds__(256) void k_final(
    const unsigned int* __restrict__ aggb,
    const float* __restrict__ bns, const float* __restrict__ bnb,
    const unsigned short* __restrict__ w1p, const float* __restrict__ b1,
    const float* __restrict__ lng, const float* __restrict__ lnb,
    const unsigned short* __restrict__ w2p, const float* __restrict__ b2,
    float* __restrict__ out)
{
    __shared__ unsigned int s_z[64 * 132];   // 33792 B; stride 132 uints
    __shared__ float s_lng[256], s_lnb[256];
    __shared__ float s_mu[64], s_iv[64];
    unsigned short* s_ts = reinterpret_cast<unsigned short*>(s_z);  // [64][264] alias

    const int tid = threadIdx.x;
    const int w = tid >> 6, lane = tid & 63, l15 = lane & 15, g = lane >> 4;
    const int n0 = blockIdx.x * 64;

    s_lng[tid] = lng[tid];
    s_lnb[tid] = lnb[tid];

    float b1v[16];
    #pragma unroll
    for (int t = 0; t < 16; ++t) b1v[t] = b1[t * 16 + l15];

    const int4* B1 = reinterpret_cast<const int4*>(w1p);
    const unsigned int* zrow_base = s_z + (w * 16 + l15) * 132;
    f32x4 acc1[16];
    #pragma unroll
    for (int t = 0; t < 16; ++t) acc1[t] = (f32x4){0.f, 0.f, 0.f, 0.f};

    const int c2 = tid & 127;
    const int rb = tid >> 7;

    #pragma unroll
    for (int c = 0; c < 2; ++c) {
        float2 sv = *reinterpret_cast<const float2*>(bns + c * 256 + 2 * c2);
        float2 bv = *reinterpret_cast<const float2*>(bnb + c * 256 + 2 * c2);
        #pragma unroll 8
        for (int i = 0; i < 32; ++i) {
            int row = rb + 2 * i;
            int ar = (n0 + row < NN) ? n0 + row : NN - 1;
            unsigned int u = aggb[(size_t)ar * 256 + c * 128 + c2];
            float z0 = fmaxf(fmaf(bf_lo(u), sv.x, bv.x), 0.f);
            float z1 = fmaxf(fmaf(bf_hi(u), sv.y, bv.y), 0.f);
            s_z[row * 132 + c2] = pack2(z0, z1);
        }
        __syncthreads();

        #pragma unroll
        for (int kk8 = 0; kk8 < 8; ++kk8) {
            const int kk = c * 8 + kk8;
            Frag16B a;
            a.i = *reinterpret_cast<const int4*>(zrow_base + kk8 * 16 + g * 4);
            #pragma unroll
            for (int t = 0; t < 16; ++t) {
                Frag16B b; b.i = B1[(kk * 16 + t) * 64 + lane];
                acc1[t] = __builtin_amdgcn_mfma_f32_16x16x32_bf16(a.s, b.s, acc1[t], 0, 0, 0);
            }
        }
        __syncthreads();
    }

    float ssum[4] = {0, 0, 0, 0}, sq[4] = {0, 0, 0, 0};
    #pragma unroll
    for (int t = 0; t < 16; ++t) {
        float bvv = b1v[t];
        #pragma unroll
        for (int r = 0; r < 4; ++r) {
            float tv = acc1[t][r] + bvv;
            ssum[r] += tv;
            sq[r] = fmaf(tv, tv, sq[r]);
            s_ts[(w * 16 + g * 4 + r) * 264 + t * 16 + l15] = f2bf(tv);
        }
    }
    #pragma unroll
    for (int m = 1; m < 16; m <<= 1) {
        #pragma unroll
        for (int r = 0; r < 4; ++r) {
            ssum[r] += __shfl_xor(ssum[r], m);
            sq[r]   += __shfl_xor(sq[r], m);
        }
    }
    if (l15 < 4) {
        float svv = l15 == 0 ? ssum[0] : l15 == 1 ? ssum[1] : l15 == 2 ? ssum[2] : ssum[3];
        float qv  = l15 == 0 ? sq[0]   : l15 == 1 ? sq[1]   : l15 == 2 ? sq[2]   : sq[3];
        float mean = svv * (1.f / 256.f);
        float var = qv * (1.f / 256.f) - mean * mean;
        s_mu[w * 16 + g * 4 + l15] = mean;
        s_iv[w * 16 + g * 4 + l15] = 1.f / sqrtf(var + 1e-5f);
    }
    __syncthreads();

    const float mu_m = s_mu[w * 16 + l15];
    const float iv_m = s_iv[w * 16 + l15];
    const int4* B2 = reinterpret_cast<const int4*>(w2p);
    const unsigned short* trow = s_ts + (w * 16 + l15) * 264;

    f32x4 acc2[8];
    #pragma unroll
    for (int t = 0; t < 8; ++t) acc2[t] = (f32x4){0.f, 0.f, 0.f, 0.f};

    #pragma unroll 2
    for (int kk = 0; kk < 8; ++kk) {
        const int kb = kk * 32 + g * 8;
        int4 traw = *reinterpret_cast<const int4*>(trow + kb);
        const unsigned short* tu = reinterpret_cast<const unsigned short*>(&traw);
        short8 af;
        #pragma unroll
        for (int j = 0; j < 8; ++j) {
            float tv = __uint_as_float(((unsigned int)tu[j]) << 16);
            float rn = fmaxf(fmaf((tv - mu_m) * iv_m, s_lng[kb + j], s_lnb[kb + j]), 0.f);
            af[j] = (short)f2bf(rn);
        }
        #pragma unroll
        for (int t = 0; t < 8; ++t) {
            Frag16B b; b.i = B2[(kk * 8 + t) * 64 + lane];
            acc2[t] = __builtin_amdgcn_mfma_f32_16x16x32_bf16(af, b.s, acc2[t], 0, 0, 0);
        }
    }

    float b2v[8];
    #pragma unroll
    for (int t = 0; t < 8; ++t) b2v[t] = b2[t * 16 + l15];

    #pragma unroll
    for (int t = 0; t < 8; ++t) {
        #pragma unroll
        for (int r = 0; r < 4; ++r) {
            int n = n0 + w * 16 + g * 4 + r;
            if (n < NN)
                out[(size_t)n * 128 + t * 16 + l15] = acc2[t][r] + b2v[t];
        }
    }
}

// ---------------------------------------------------------------------------
extern "C" void kernel_launch(void* const* d_in, const int* in_sizes, int n_in,
                              void* d_out, int out_size, void* d_ws, size_t ws_size,
                              hipStream_t stream)
{
    const float* x    = (const float*)d_in[0];
    const int*   ei   = (const int*)d_in[1];
    const float* pos  = (const float*)d_in[2];
    const float* wft  = (const float*)d_in[3];
    const float* bft  = (const float*)d_in[4];
    const float* wcv  = (const float*)d_in[5];
    const float* bcv  = (const float*)d_in[6];
    const float* vfp  = (const float*)d_in[7];
    const float* vpar = (const float*)d_in[8];
    const float* bng  = (const float*)d_in[9];
    const float* bnbe = (const float*)d_in[10];
    const float* att  = (const float*)d_in[11];
    const float* w1   = (const float*)d_in[12];
    const float* b1   = (const float*)d_in[13];
    const float* lng  = (const float*)d_in[14];
    const float* lnb  = (const float*)d_in[15];
    const float* w2   = (const float*)d_in[16];
    const float* b2   = (const float*)d_in[17];
    float* out = (float*)d_out;

    float* ws = (float*)d_ws;
    size_t off = 0;
    unsigned int* msg  = (unsigned int*)(ws + off); off += (size_t)NN * 64;    // bf16 [N][128]
    unsigned int* aggb = (unsigned int*)(ws + off); off += (size_t)NN * 256;   // bf16 [N][512]
    unsigned short* w1p  = (unsigned short*)(ws + off); off += 65536;
    unsigned short* w2p  = (unsigned short*)(ws + off); off += 16384;
    unsigned short* wftp = (unsigned short*)(ws + off); off += 8192;
    unsigned short* wcvp = (unsigned short*)(ws + off); off += 8192;
    float4* pos4 = (float4*)(ws + off); off += (size_t)NN * 4;
    float* bns  = ws + off; off += 512;
    float* bnbv = ws + off; off += 512;
    float4* dde = (float4*)(ws + off); off += (size_t)EE * 4;   // {dist,dsum,s,d}
    uint4* csre = (uint4*)(ws + off); off += (size_t)EE * 4;    // {src, ab01, ab23, pad}
    int* offs   = (int*)(ws + off); off += NN + 4;
    int* loc    = (int*)(ws + off); off += NN;
    int* bsum   = (int*)(ws + off); off += 256;
    int* bofs   = (int*)(ws + off); off += 256;
    float* blockmax = ws + off; off += 3136;
    float* dmax = ws + off; off += 4;
    size_t zstart = off;
    float* bn_psum = ws + off; off += 32 * 512;
    float* bn_psq  = ws + off; off += 32 * 512;
    int* counts = (int*)(ws + off); off += NN;
    int* cursor = (int*)(ws + off); off += NN;
    size_t zend = off;

    hipMemsetAsync(ws + zstart, 0, (zend - zstart) * sizeof(float), stream);

    k_prep<<<196, 256, 0, stream>>>(w1, att, w2, wft, wcv, pos, w1p, w2p, wftp, wcvp, pos4);
    k_ft_conv<<<782, 256, 0, stream>>>(x, wftp, bft, wcvp, bcv, msg);
    k_edge_pass1<<<3125, 256, 0, stream>>>(ei, pos4, blockmax, counts, dde);
    k_scan1<<<196, 256, 0, stream>>>(counts, loc, bsum);
    k_scan2dmax<<<2, 256, 0, stream>>>(bsum, bofs, 196, blockmax, dmax, 3125);
    k_scan3<<<196, 256, 0, stream>>>(loc, bofs, offs);
    k_fill<<<3125, 256, 0, stream>>>(dde, dmax, vfp, vpar, offs, cursor, csre);
    k_agg<<<12500, 256, 0, stream>>>(offs, csre, msg, aggb);
    k_bnstats<<<1563, 256, 0, stream>>>((const uint2*)aggb, bn_psum, bn_psq);
    k_bnfin<<<2, 256, 0, stream>>>(bn_psum, bn_psq, bng, bnbe, bns, bnbv);
    k_final<<<782, 256, 0, stream>>>(aggb, bns, bnbv, w1p, b1, lng, lnb, w2p, b2, out);
}

// Round 9
// 383.625 us; speedup vs baseline: 1.1539x; 1.1539x over previous
//
#include <hip/hip_runtime.h>
#include <hip/hip_bf16.h>

#define NN 50000
#define EE 800000

typedef short short8 __attribute__((ext_vector_type(8)));
typedef float f32x4 __attribute__((ext_vector_type(4)));

union Frag16B { short8 s; int4 i; };
union H4 { _Float16 h[4]; uint2 u; };

static __device__ __forceinline__ unsigned short f2bf(float f) {
    union { float f; unsigned u; } v; v.f = f;
    unsigned r = v.u + 0x7FFF + ((v.u >> 16) & 1);   // RNE
    return (unsigned short)(r >> 16);
}
static __device__ __forceinline__ float bf_lo(unsigned int u) {
    return __uint_as_float(u << 16);
}
static __device__ __forceinline__ float bf_hi(unsigned int u) {
    return __uint_as_float(u & 0xFFFF0000u);
}
static __device__ __forceinline__ unsigned int pack2(float a, float b) {
    return (unsigned int)f2bf(a) | ((unsigned int)f2bf(b) << 16);
}

// ---------------- prep: fragment-major bf16 weight packing + pos->float4 ----
__global__ __launch_bounds__(256) void k_prep(
    const float* __restrict__ w1,  const float* __restrict__ att,
    const float* __restrict__ w2,
    const float* __restrict__ wft, const float* __restrict__ wcv,
    const float* __restrict__ pos,
    unsigned short* __restrict__ w1p, unsigned short* __restrict__ w2p,
    unsigned short* __restrict__ wftp, unsigned short* __restrict__ wcvp,
    float4* __restrict__ pos4)
{
    int gth = blockIdx.x * 256 + threadIdx.x;
    int lane = gth & 63, l15 = lane & 15, gg = lane >> 4;
    if (gth < 16384) {                       // w1p: kk<16, t<16, fold att[col]
        int t = (gth >> 6) & 15, kk = gth >> 10;
        int row = t * 16 + l15, c0 = kk * 32 + gg * 8;
        unsigned int pk[4];
        #pragma unroll
        for (int j = 0; j < 4; ++j) {
            int c = c0 + 2 * j;
            pk[j] = pack2(w1[row * 512 + c] * att[c],
                          w1[row * 512 + c + 1] * att[c + 1]);
        }
        *reinterpret_cast<uint4*>(w1p + (size_t)gth * 8) = make_uint4(pk[0], pk[1], pk[2], pk[3]);
    }
    if (gth < 4096) {                        // w2p: kk<8, t<8
        int t = (gth >> 6) & 7, kk = gth >> 9;
        int row = t * 16 + l15, c0 = kk * 32 + gg * 8;
        unsigned int pk[4];
        #pragma unroll
        for (int j = 0; j < 4; ++j) {
            int c = c0 + 2 * j;
            pk[j] = pack2(w2[row * 256 + c], w2[row * 256 + c + 1]);
        }
        *reinterpret_cast<uint4*>(w2p + (size_t)gth * 8) = make_uint4(pk[0], pk[1], pk[2], pk[3]);
    }
    if (gth < 2048) {                        // wftp / wcvp: kk<4, t<8
        int t = (gth >> 6) & 7, kk = gth >> 9;
        int row = t * 16 + l15, c0 = kk * 32 + gg * 8;
        unsigned int pa[4], pb[4];
        #pragma unroll
        for (int j = 0; j < 4; ++j) {
            int c = c0 + 2 * j;
            pa[j] = pack2(wft[row * 128 + c], wft[row * 128 + c + 1]);
            pb[j] = pack2(wcv[row * 128 + c], wcv[row * 128 + c + 1]);
        }
        *reinterpret_cast<uint4*>(wftp + (size_t)gth * 8) = make_uint4(pa[0], pa[1], pa[2], pa[3]);
        *reinterpret_cast<uint4*>(wcvp + (size_t)gth * 8) = make_uint4(pb[0], pb[1], pb[2], pb[3]);
    }
    if (gth < NN) {                          // pos -> padded float4
        pos4[gth] = make_float4(pos[gth * 3 + 0], pos[gth * 3 + 1], pos[gth * 3 + 2], 0.f);
    }
}

// ---------------- fused node GEMMs (MFMA): msg = (relu(x WftT+bft)) WcvT + bcv
__global__ __launch_bounds__(256) void k_ft_conv(
    const float* __restrict__ x,
    const unsigned short* __restrict__ wftp, const float* __restrict__ bft,
    const unsigned short* __restrict__ wcvp, const float* __restrict__ bcv,
    unsigned int* __restrict__ msg)          // bf16 [NN][128] as uint[NN][64]
{
    __shared__ unsigned int s_x[64 * 68];    // bf16 tile (reused for out)
    __shared__ unsigned short s_h[64 * 136];
    const int tid = threadIdx.x;
    const int w = tid >> 6, lane = tid & 63, l15 = lane & 15, g = lane >> 4;
    const int n0 = blockIdx.x * 64;

    #pragma unroll
    for (int i = 0; i < 8; ++i) {
        int lin = tid + i * 256;
        int row = lin >> 5, c4 = lin & 31;
        int ar = (n0 + row < NN) ? n0 + row : NN - 1;
        float4 v = *reinterpret_cast<const float4*>(x + (size_t)ar * 128 + c4 * 4);
        s_x[row * 68 + c4 * 2]     = pack2(v.x, v.y);
        s_x[row * 68 + c4 * 2 + 1] = pack2(v.z, v.w);
    }
    __syncthreads();

    float bftv[8], bcvv[8];
    #pragma unroll
    for (int t = 0; t < 8; ++t) { bftv[t] = bft[t * 16 + l15]; bcvv[t] = bcv[t * 16 + l15]; }

    const int4* Bf = reinterpret_cast<const int4*>(wftp);
    f32x4 acc[8];
    #pragma unroll
    for (int t = 0; t < 8; ++t) acc[t] = (f32x4){0.f, 0.f, 0.f, 0.f};
    #pragma unroll
    for (int kk = 0; kk < 4; ++kk) {
        Frag16B a;
        a.i = *reinterpret_cast<const int4*>(&s_x[(w * 16 + l15) * 68 + kk * 16 + g * 4]);
        #pragma unroll
        for (int t = 0; t < 8; ++t) {
            Frag16B b; b.i = Bf[(kk * 8 + t) * 64 + lane];
            acc[t] = __builtin_amdgcn_mfma_f32_16x16x32_bf16(a.s, b.s, acc[t], 0, 0, 0);
        }
    }
    #pragma unroll
    for (int t = 0; t < 8; ++t)
        #pragma unroll
        for (int r = 0; r < 4; ++r)
            s_h[(w * 16 + g * 4 + r) * 136 + t * 16 + l15] =
                f2bf(fmaxf(acc[t][r] + bftv[t], 0.f));
    __syncthreads();

    const int4* Bc = reinterpret_cast<const int4*>(wcvp);
    #pragma unroll
    for (int t = 0; t < 8; ++t) acc[t] = (f32x4){0.f, 0.f, 0.f, 0.f};
    #pragma unroll
    for (int kk = 0; kk < 4; ++kk) {
        Frag16B a;
        a.i = *reinterpret_cast<const int4*>(&s_h[(w * 16 + l15) * 136 + kk * 32 + g * 8]);
        #pragma unroll
        for (int t = 0; t < 8; ++t) {
            Frag16B b; b.i = Bc[(kk * 8 + t) * 64 + lane];
            acc[t] = __builtin_amdgcn_mfma_f32_16x16x32_bf16(a.s, b.s, acc[t], 0, 0, 0);
        }
    }
    unsigned short* s_o = reinterpret_cast<unsigned short*>(s_x);
    #pragma unroll
    for (int t = 0; t < 8; ++t)
        #pragma unroll
        for (int r = 0; r < 4; ++r)
            s_o[(w * 16 + g * 4 + r) * 136 + t * 16 + l15] = f2bf(acc[t][r] + bcvv[t]);
    __syncthreads();
    #pragma unroll
    for (int i = 0; i < 8; ++i) {
        int lin = tid + i * 256;
        int row = lin >> 5, cu2 = lin & 31;
        if (n0 + row < NN) {
            uint2 v;
            v.x = s_x[row * 68 + cu2 * 2];
            v.y = s_x[row * 68 + cu2 * 2 + 1];
            *reinterpret_cast<uint2*>(msg + (size_t)(n0 + row) * 64 + cu2 * 2) = v;
        }
    }
}

// ---------------- edge pass 1: {dist,dsum,s,d} record + degree + block max --
__global__ __launch_bounds__(256) void k_edge_pass1(
    const int* __restrict__ ei, const float4* __restrict__ pos4,
    float* __restrict__ blockmax, int* __restrict__ counts,
    float4* __restrict__ dde)
{
    __shared__ float smax[4];
    int e = blockIdx.x * 256 + threadIdx.x;       // grid covers EE exactly
    int s = ei[e], d = ei[EE + e];
    float4 ps = pos4[s], pd = pos4[d];
    float dx = ps.x - pd.x, dy = ps.y - pd.y, dz = ps.z - pd.z;
    float dist = sqrtf(dx * dx + dy * dy + dz * dz);
    float rinv = 1.f / (dist + 1e-8f);
    dde[e] = make_float4(dist, (dx + dy + dz) * rinv,
                         __int_as_float(s), __int_as_float(d));
    atomicAdd(&counts[d], 1);

    float m = dist;
    #pragma unroll
    for (int o = 32; o >= 1; o >>= 1)
        m = fmaxf(m, __shfl_xor(m, o));
    if ((threadIdx.x & 63) == 0) smax[threadIdx.x >> 6] = m;
    __syncthreads();
    if (threadIdx.x == 0)
        blockmax[blockIdx.x] = fmaxf(fmaxf(smax[0], smax[1]), fmaxf(smax[2], smax[3]));
}

// ---------------- 3-kernel exclusive scan over counts -----------------------
__global__ __launch_bounds__(256) void k_scan1(const int* __restrict__ counts,
    int* __restrict__ loc, int* __restrict__ bsum)
{
    __shared__ int sd[256];
    int i = blockIdx.x * 256 + threadIdx.x;
    int v = (i < NN) ? counts[i] : 0;
    sd[threadIdx.x] = v;
    __syncthreads();
    for (int ofs = 1; ofs < 256; ofs <<= 1) {
        int t = (threadIdx.x >= ofs) ? sd[threadIdx.x - ofs] : 0;
        __syncthreads();
        sd[threadIdx.x] += t;
        __syncthreads();
    }
    int incl = sd[threadIdx.x];
    if (i < NN) loc[i] = incl - v;
    if (threadIdx.x == 255) bsum[blockIdx.x] = incl;
}

// block 0: exclusive scan of bsum; block 1: dmax reduce over blockmax
__global__ __launch_bounds__(256) void k_scan2dmax(const int* __restrict__ bsum,
    int* __restrict__ bofs, int nb,
    const float* __restrict__ blockmax, float* __restrict__ dmax, int nmb)
{
    if (blockIdx.x == 0) {
        __shared__ int sd[256];
        int v = (threadIdx.x < nb) ? bsum[threadIdx.x] : 0;
        sd[threadIdx.x] = v;
        __syncthreads();
        for (int ofs = 1; ofs < 256; ofs <<= 1) {
            int t = (threadIdx.x >= ofs) ? sd[threadIdx.x - ofs] : 0;
            __syncthreads();
            sd[threadIdx.x] += t;
            __syncthreads();
        }
        bofs[threadIdx.x] = sd[threadIdx.x] - v;
    } else {
        __shared__ float smax[4];
        float m = 0.f;
        for (int i = threadIdx.x; i < nmb; i += 256) m = fmaxf(m, blockmax[i]);
        #pragma unroll
        for (int o = 32; o >= 1; o >>= 1)
            m = fmaxf(m, __shfl_xor(m, o));
        if ((threadIdx.x & 63) == 0) smax[threadIdx.x >> 6] = m;
        __syncthreads();
        if (threadIdx.x == 0)
            dmax[0] = fmaxf(fmaxf(smax[0], smax[1]), fmaxf(smax[2], smax[3]));
    }
}

__global__ __launch_bounds__(256) void k_scan3(const int* __restrict__ loc,
    const int* __restrict__ bofs, int* __restrict__ offs)
{
    int i = blockIdx.x * 256 + threadIdx.x;
    if (i < NN) offs[i] = loc[i] + bofs[blockIdx.x];
    if (i == 0) offs[NN] = EE;
}

// ---------------- edge pass 2: ab factors + packed CSR record ---------------
__global__ __launch_bounds__(256) void k_fill(
    const float4* __restrict__ dde,
    const float* __restrict__ dmaxp,
    const float* __restrict__ vfp, const float* __restrict__ vpar,
    const int* __restrict__ offs, int* __restrict__ cursor,
    uint4* __restrict__ csre)
{
    int e = blockIdx.x * 256 + threadIdx.x;       // grid covers EE exactly
    float4 v4 = dde[e];
    int s = __float_as_int(v4.z), d = __float_as_int(v4.w);
    float r = v4.x / dmaxp[0];
    float dsum = v4.y;
    float vf = vfp[0];
    H4 p;
    #pragma unroll
    for (int k = 0; k < 4; ++k) {
        float v = vf * fminf(r, vpar[k]);
        p.h[k] = (_Float16)(sqrtf(1.f - v * v + 1e-8f) / (1.f + v * dsum));
    }
    int slot = offs[d] + atomicAdd(&cursor[d], 1);
    csre[slot] = make_uint4((unsigned)s, p.u.x, p.u.y, 0u);
}

// ---------------- aggregation: one wave per node, 8x unrolled gathers -------
__global__ __launch_bounds__(256) void k_agg(
    const int* __restrict__ offs, const uint4* __restrict__ csre,
    const unsigned int* __restrict__ msg,
    unsigned int* __restrict__ aggb)         // bf16 [NN][512] as uint[NN][256]
{
    int lane = threadIdx.x & 63;
    int n = blockIdx.x * 4 + (threadIdx.x >> 6);
    if (n >= NN) return;
    int st = offs[n], en = offs[n + 1];
    float a00 = 0, a10 = 0, a20 = 0, a30 = 0, a01 = 0, a11 = 0, a21 = 0, a31 = 0;

    int e = st;
    for (; e + 8 <= en; e += 8) {
        uint4 rr[8];
        unsigned int uu[8];
        #pragma unroll
        for (int j = 0; j < 8; ++j) rr[j] = csre[e + j];
        #pragma unroll
        for (int j = 0; j < 8; ++j) uu[j] = msg[(size_t)rr[j].x * 64 + lane];
        #pragma unroll
        for (int j = 0; j < 8; ++j) {
            H4 p; p.u = make_uint2(rr[j].y, rr[j].z);
            float m0 = bf_lo(uu[j]), m1 = bf_hi(uu[j]);
            a00 = fmaf((float)p.h[0], m0, a00); a01 = fmaf((float)p.h[0], m1, a01);
            a10 = fmaf((float)p.h[1], m0, a10); a11 = fmaf((float)p.h[1], m1, a11);
            a20 = fmaf((float)p.h[2], m0, a20); a21 = fmaf((float)p.h[2], m1, a21);
            a30 = fmaf((float)p.h[3], m0, a30); a31 = fmaf((float)p.h[3], m1, a31);
        }
    }
    for (; e < en; ++e) {
        uint4 rr = csre[e];
        unsigned int u = msg[(size_t)rr.x * 64 + lane];
        H4 p; p.u = make_uint2(rr.y, rr.z);
        float m0 = bf_lo(u), m1 = bf_hi(u);
        a00 = fmaf((float)p.h[0], m0, a00); a01 = fmaf((float)p.h[0], m1, a01);
        a10 = fmaf((float)p.h[1], m0, a10); a11 = fmaf((float)p.h[1], m1, a11);
        a20 = fmaf((float)p.h[2], m0, a20); a21 = fmaf((float)p.h[2], m1, a21);
        a30 = fmaf((float)p.h[3], m0, a30); a31 = fmaf((float)p.h[3], m1, a31);
    }

    unsigned int* o = aggb + (size_t)n * 256 + lane;   // col c = k*128 + h
    o[0]   = pack2(a00, a01);
    o[64]  = pack2(a10, a11);
    o[128] = pack2(a20, a21);
    o[192] = pack2(a30, a31);
}

// ---------------- BN stats: 32-row stripes into 32 partial buffers ----------
__global__ __launch_bounds__(256) void k_bnstats(const uint2* __restrict__ aggb2,
    float* __restrict__ bn_psum, float* __restrict__ bn_psq)
{
    int c2 = threadIdx.x & 127;              // uint2 col (owns cols 4*c2..4*c2+3)
    int rbase = blockIdx.x * 32 + (threadIdx.x >> 7);
    float s0 = 0, s1 = 0, s2 = 0, s3 = 0, q0 = 0, q1 = 0, q2 = 0, q3 = 0;
    #pragma unroll 8
    for (int i = 0; i < 16; ++i) {
        int r = rbase + 2 * i;
        if (r < NN) {
            uint2 u = aggb2[(size_t)r * 128 + c2];
            float v0 = bf_lo(u.x), v1 = bf_hi(u.x);
            float v2 = bf_lo(u.y), v3 = bf_hi(u.y);
            s0 += v0; s1 += v1; s2 += v2; s3 += v3;
            q0 = fmaf(v0, v0, q0); q1 = fmaf(v1, v1, q1);
            q2 = fmaf(v2, v2, q2); q3 = fmaf(v3, v3, q3);
        }
    }
    int part = (blockIdx.x & 31) * 512;
    int c0 = c2 * 4;
    atomicAdd(&bn_psum[part + c0], s0);     atomicAdd(&bn_psum[part + c0 + 1], s1);
    atomicAdd(&bn_psum[part + c0 + 2], s2); atomicAdd(&bn_psum[part + c0 + 3], s3);
    atomicAdd(&bn_psq[part + c0], q0);      atomicAdd(&bn_psq[part + c0 + 1], q1);
    atomicAdd(&bn_psq[part + c0 + 2], q2);  atomicAdd(&bn_psq[part + c0 + 3], q3);
}

__global__ __launch_bounds__(256) void k_bnfin(const float* __restrict__ bn_psum,
    const float* __restrict__ bn_psq, const float* __restrict__ bng,
    const float* __restrict__ bnbeta, float* __restrict__ bns, float* __restrict__ bnbv)
{
    int c = blockIdx.x * 256 + threadIdx.x;
    if (c >= 512) return;
    float s = 0.f, q = 0.f;
    #pragma unroll 8
    for (int p = 0; p < 32; ++p) {
        s += bn_psum[p * 512 + c];
        q += bn_psq[p * 512 + c];
    }
    float mean = s * (1.f / NN);
    float var = q * (1.f / NN) - mean * mean;
    float sc = bng[c] / sqrtf(var + 1e-5f);
    bns[c] = sc;
    bnbv[c] = bnbeta[c] - mean * sc;
}

// ---------------- final fused MFMA: col-split waves, 32-node tile -----------
// Block = 4 waves = 2 node-groups (ng) x 2 col-halves (ch). Wave: 16 nodes x
// 128 GEMM1 cols (acc1[8]=32 AGPR) and 16 nodes x 64 GEMM2 cols (acc2[4]=16).
// Total ~118 regs -> 4 waves/EU (unified VGPR/AGPR file was the R8 wall:
// 116 VGPR + 64 AGPR = 180 -> 2 waves/EU). Full z stage (no chunking — R8's
// chunk barriers serialized staging/compute). LN = 2-wave LDS partials.
__global__ __launch_bounds__(256) void k_final(
    const unsigned int* __restrict__ aggb,
    const float* __restrict__ bns, const float* __restrict__ bnb,
    const unsigned short* __restrict__ w1p, const float* __restrict__ b1,
    const float* __restrict__ lng, const float* __restrict__ lnb,
    const unsigned short* __restrict__ w2p, const float* __restrict__ b2,
    float* __restrict__ out)
{
    __shared__ unsigned int s_z[32 * 260];   // 33280 B; t matrix aliases below
    __shared__ float s_lng[256], s_lnb[256];
    __shared__ float s_ps[2][32], s_pq[2][32];
    __shared__ float s_mu[32], s_iv[32];
    unsigned short* s_ts = reinterpret_cast<unsigned short*>(s_z);  // [32][264]

    const int tid = threadIdx.x;
    const int w = tid >> 6, lane = tid & 63, l15 = lane & 15, g = lane >> 4;
    const int ng = w & 1, ch = w >> 1;
    const int n0 = blockIdx.x * 32;

    s_lng[tid] = lng[tid];
    s_lnb[tid] = lnb[tid];

    // stage z = bf16(relu(agg*scale+shift)); thread owns uint col = tid
    float2 sv = *reinterpret_cast<const float2*>(bns + 2 * tid);
    float2 bv = *reinterpret_cast<const float2*>(bnb + 2 * tid);
    #pragma unroll 8
    for (int i = 0; i < 32; ++i) {
        int ar = (n0 + i < NN) ? n0 + i : NN - 1;
        unsigned int u = aggb[(size_t)ar * 256 + tid];
        float z0 = fmaxf(fmaf(bf_lo(u), sv.x, bv.x), 0.f);
        float z1 = fmaxf(fmaf(bf_hi(u), sv.y, bv.y), 0.f);
        s_z[i * 260 + tid] = pack2(z0, z1);
    }
    __syncthreads();

    // ---------------- GEMM1: rows ng*16+l15, out tiles ch*8+j (j<8) ---------
    const unsigned int* zrow = s_z + (ng * 16 + l15) * 260;
    const int4* B1 = reinterpret_cast<const int4*>(w1p);
    f32x4 acc1[8];
    #pragma unroll
    for (int j = 0; j < 8; ++j) acc1[j] = (f32x4){0.f, 0.f, 0.f, 0.f};

    #pragma unroll 2
    for (int kk = 0; kk < 16; ++kk) {
        Frag16B a;
        a.i = *reinterpret_cast<const int4*>(zrow + kk * 16 + g * 4);
        #pragma unroll
        for (int j = 0; j < 8; ++j) {
            Frag16B b; b.i = B1[(kk * 16 + ch * 8 + j) * 64 + lane];
            acc1[j] = __builtin_amdgcn_mfma_f32_16x16x32_bf16(a.s, b.s, acc1[j], 0, 0, 0);
        }
    }
    __syncthreads();   // all z reads done before t overwrites the buffer

    // ---------------- bias + t stash + LN partials (per col-half) -----------
    float b1v[8];
    #pragma unroll
    for (int j = 0; j < 8; ++j) b1v[j] = b1[(ch * 8 + j) * 16 + l15];

    float ssum[4] = {0, 0, 0, 0}, sq[4] = {0, 0, 0, 0};
    #pragma unroll
    for (int j = 0; j < 8; ++j) {
        float bvv = b1v[j];
        #pragma unroll
        for (int r = 0; r < 4; ++r) {
            float tv = acc1[j][r] + bvv;
            ssum[r] += tv;
            sq[r] = fmaf(tv, tv, sq[r]);
            s_ts[(ng * 16 + g * 4 + r) * 264 + (ch * 8 + j) * 16 + l15] = f2bf(tv);
        }
    }
    #pragma unroll
    for (int m = 1; m < 16; m <<= 1) {
        #pragma unroll
        for (int r = 0; r < 4; ++r) {
            ssum[r] += __shfl_xor(ssum[r], m);
            sq[r]   += __shfl_xor(sq[r], m);
        }
    }
    if (l15 < 4) {
        float svv = l15 == 0 ? ssum[0] : l15 == 1 ? ssum[1] : l15 == 2 ? ssum[2] : ssum[3];
        float qv  = l15 == 0 ? sq[0]   : l15 == 1 ? sq[1]   : l15 == 2 ? sq[2]   : sq[3];
        s_ps[ch][ng * 16 + g * 4 + l15] = svv;
        s_pq[ch][ng * 16 + g * 4 + l15] = qv;
    }
    __syncthreads();

    if (tid < 32) {
        float s = s_ps[0][tid] + s_ps[1][tid];
        float q = s_pq[0][tid] + s_pq[1][tid];
        float mean = s * (1.f / 256.f);
        float var = q * (1.f / 256.f) - mean * mean;
        s_mu[tid] = mean;
        s_iv[tid] = 1.f / sqrtf(var + 1e-5f);
    }
    __syncthreads();

    // ---------------- GEMM2: K=256 over t; out tiles ch*4+j (j<4) -----------
    const float mu_m = s_mu[ng * 16 + l15];
    const float iv_m = s_iv[ng * 16 + l15];
    const int4* B2 = reinterpret_cast<const int4*>(w2p);
    const unsigned short* trow = s_ts + (ng * 16 + l15) * 264;

    f32x4 acc2[4];
    #pragma unroll
    for (int j = 0; j < 4; ++j) acc2[j] = (f32x4){0.f, 0.f, 0.f, 0.f};

    #pragma unroll 2
    for (int kk = 0; kk < 8; ++kk) {
        const int kb = kk * 32 + g * 8;
        int4 traw = *reinterpret_cast<const int4*>(trow + kb);
        const unsigned short* tu = reinterpret_cast<const unsigned short*>(&traw);
        short8 af;
        #pragma unroll
        for (int j = 0; j < 8; ++j) {
            float tv = __uint_as_float(((unsigned int)tu[j]) << 16);
            float rn = fmaxf(fmaf((tv - mu_m) * iv_m, s_lng[kb + j], s_lnb[kb + j]), 0.f);
            af[j] = (short)f2bf(rn);
        }
        #pragma unroll
        for (int j = 0; j < 4; ++j) {
            Frag16B b; b.i = B2[(kk * 8 + ch * 4 + j) * 64 + lane];
            acc2[j] = __builtin_amdgcn_mfma_f32_16x16x32_bf16(af, b.s, acc2[j], 0, 0, 0);
        }
    }

    float b2v[4];
    #pragma unroll
    for (int j = 0; j < 4; ++j) b2v[j] = b2[(ch * 4 + j) * 16 + l15];

    #pragma unroll
    for (int j = 0; j < 4; ++j) {
        #pragma unroll
        for (int r = 0; r < 4; ++r) {
            int n = n0 + ng * 16 + g * 4 + r;
            if (n < NN)
                out[(size_t)n * 128 + (ch * 4 + j) * 16 + l15] = acc2[j][r] + b2v[j];
        }
    }
}

// ---------------------------------------------------------------------------
extern "C" void kernel_launch(void* const* d_in, const int* in_sizes, int n_in,
                              void* d_out, int out_size, void* d_ws, size_t ws_size,
                              hipStream_t stream)
{
    const float* x    = (const float*)d_in[0];
    const int*   ei   = (const int*)d_in[1];
    const float* pos  = (const float*)d_in[2];
    const float* wft  = (const float*)d_in[3];
    const float* bft  = (const float*)d_in[4];
    const float* wcv  = (const float*)d_in[5];
    const float* bcv  = (const float*)d_in[6];
    const float* vfp  = (const float*)d_in[7];
    const float* vpar = (const float*)d_in[8];
    const float* bng  = (const float*)d_in[9];
    const float* bnbe = (const float*)d_in[10];
    const float* att  = (const float*)d_in[11];
    const float* w1   = (const float*)d_in[12];
    const float* b1   = (const float*)d_in[13];
    const float* lng  = (const float*)d_in[14];
    const float* lnb  = (const float*)d_in[15];
    const float* w2   = (const float*)d_in[16];
    const float* b2   = (const float*)d_in[17];
    float* out = (float*)d_out;

    float* ws = (float*)d_ws;
    size_t off = 0;
    unsigned int* msg  = (unsigned int*)(ws + off); off += (size_t)NN * 64;    // bf16 [N][128]
    unsigned int* aggb = (unsigned int*)(ws + off); off += (size_t)NN * 256;   // bf16 [N][512]
    unsigned short* w1p  = (unsigned short*)(ws + off); off += 65536;
    unsigned short* w2p  = (unsigned short*)(ws + off); off += 16384;
    unsigned short* wftp = (unsigned short*)(ws + off); off += 8192;
    unsigned short* wcvp = (unsigned short*)(ws + off); off += 8192;
    float4* pos4 = (float4*)(ws + off); off += (size_t)NN * 4;
    float* bns  = ws + off; off += 512;
    float* bnbv = ws + off; off += 512;
    float4* dde = (float4*)(ws + off); off += (size_t)EE * 4;   // {dist,dsum,s,d}
    uint4* csre = (uint4*)(ws + off); off += (size_t)EE * 4;    // {src, ab01, ab23, pad}
    int* offs   = (int*)(ws + off); off += NN + 4;
    int* loc    = (int*)(ws + off); off += NN;
    int* bsum   = (int*)(ws + off); off += 256;
    int* bofs   = (int*)(ws + off); off += 256;
    float* blockmax = ws + off; off += 3136;
    float* dmax = ws + off; off += 4;
    size_t zstart = off;
    float* bn_psum = ws + off; off += 32 * 512;
    float* bn_psq  = ws + off; off += 32 * 512;
    int* counts = (int*)(ws + off); off += NN;
    int* cursor = (int*)(ws + off); off += NN;
    size_t zend = off;

    hipMemsetAsync(ws + zstart, 0, (zend - zstart) * sizeof(float), stream);

    k_prep<<<196, 256, 0, stream>>>(w1, att, w2, wft, wcv, pos, w1p, w2p, wftp, wcvp, pos4);
    k_ft_conv<<<782, 256, 0, stream>>>(x, wftp, bft, wcvp, bcv, msg);
    k_edge_pass1<<<3125, 256, 0, stream>>>(ei, pos4, blockmax, counts, dde);
    k_scan1<<<196, 256, 0, stream>>>(counts, loc, bsum);
    k_scan2dmax<<<2, 256, 0, stream>>>(bsum, bofs, 196, blockmax, dmax, 3125);
    k_scan3<<<196, 256, 0, stream>>>(loc, bofs, offs);
    k_fill<<<3125, 256, 0, stream>>>(dde, dmax, vfp, vpar, offs, cursor, csre);
    k_agg<<<12500, 256, 0, stream>>>(offs, csre, msg, aggb);
    k_bnstats<<<1563, 256, 0, stream>>>((const uint2*)aggb, bn_psum, bn_psq);
    k_bnfin<<<2, 256, 0, stream>>>(bn_psum, bn_psq, bng, bnbe, bns, bnbv);
    k_final<<<1563, 256, 0, stream>>>(aggb, bns, bnbv, w1p, b1, lng, lnb, w2p, b2, out);
}